// Round 9
// baseline (8132.852 us; speedup 1.0000x reference)
//
#include <hip/hip_runtime.h>
#include <hip/hip_bf16.h>
#include <cstddef>

// ---------------- problem constants ----------------
constexpr int kN = 32768;          // nodes
constexpr int kE = 524288;         // edges
constexpr int kB = 64;             // graphs
constexpr int kL = 4;              // layers
constexpr float kGamma = (float)(1.0 / (0.5625 + 1e-8));  // 1/((12/16)^2+1e-8)
constexpr float kLnEps = 1e-5f;

#define DI __device__ __forceinline__

typedef __attribute__((ext_vector_type(8))) short bf16x8;
typedef __attribute__((ext_vector_type(4))) short s16x4;
typedef __attribute__((ext_vector_type(4))) float f32x4;
#define MFMA16(a, b, c) __builtin_amdgcn_mfma_f32_16x16x32_bf16(a, b, c, 0, 0, 0)

DI float siluf(float x) { return x / (1.f + __expf(-x)); }
DI float sigmf(float x) { return 1.f / (1.f + __expf(-x)); }
DI unsigned short f2bf(float x) {
  __hip_bfloat16 b = __float2bfloat16(x);
  return *(unsigned short*)&b;
}
DI float b2f(unsigned short u) {
  union { unsigned i; float f; } c; c.i = ((unsigned)u) << 16; return c.f;
}
// load 8 consecutive fp32, convert to a bf16x8 A/B fragment
DI bf16x8 ldA(const float* p) {
  const float4 a = *(const float4*)p;
  const float4 b = *(const float4*)(p + 4);
  bf16x8 r;
  r[0] = (short)f2bf(a.x); r[1] = (short)f2bf(a.y);
  r[2] = (short)f2bf(a.z); r[3] = (short)f2bf(a.w);
  r[4] = (short)f2bf(b.x); r[5] = (short)f2bf(b.y);
  r[6] = (short)f2bf(b.z); r[7] = (short)f2bf(b.w);
  return r;
}

// ---------------- B^T builder kernels (bf16, [col][k], row stride K) ----------------
__global__ void k_btA(const float* src, unsigned short* dst, int K) {
  int idx = blockIdx.x * 256 + threadIdx.x;  // K*128 threads; src is [K][128]
  if (idx >= K * 128) return;
  int c = idx & 127, k = idx >> 7;
  dst[c * K + k] = f2bf(src[(size_t)k * 128 + c]);
}

__global__ void k_bt1(const float* w, unsigned short* dst) {
  int idx = blockIdx.x * 256 + threadIdx.x;  // 128*224
  int c = idx & 127, k = idx >> 7;
  dst[c * 224 + k] = f2bf(k < 203 ? w[(size_t)k * 128 + c] : 0.f);
}

__global__ void k_btPQ(const float* w1, unsigned short* dst) {
  int idx = blockIdx.x * 256 + threadIdx.x;  // 256*160
  int cc = idx / 160, k = idx - cc * 160;
  int c = cc & 127, half = cc >> 7;
  float v = 0.f;
  if (k < 128) v = w1[(size_t)(half * 128 + k) * 128 + c];
  else if (k < 144) v = w1[(size_t)(321 + half * 16 + (k - 128)) * 128 + c];
  dst[idx] = f2bf(v);
}

// w2gw[k][t] = sum_j w2[k][j]*gw[j][t]; [2048..2063]: gb2[t] = gb[t] + sum_j b2[j]*gw[j][t]
__global__ void k_w2gw(const float* w2, const float* gw, const float* b2, const float* gb,
                       float* out) {
  int idx = blockIdx.x * 256 + threadIdx.x;
  if (idx < 2048) {
    int k = idx >> 4, t = idx & 15;
    float a = 0.f;
    for (int j = 0; j < 128; j++) a += w2[(size_t)k * 128 + j] * gw[j * 16 + t];
    out[idx] = a;
  } else if (idx < 2064) {
    int t = idx - 2048;
    float a = gb[t];
    for (int j = 0; j < 128; j++) a += b2[j] * gw[j * 16 + t];
    out[idx] = a;
  }
}

// transpose composed gate weights to bf16 [t][128]
__global__ void k_gwT(const float* w2gw, unsigned short* dst) {
  int idx = blockIdx.x * 256 + threadIdx.x;  // 2048
  int k = idx >> 4, t = idx & 15;
  dst[t * 128 + k] = f2bf(w2gw[idx]);
}

// xrest[N][96]: reschem(6)|role(2)|misc(3)|rbf(64)|pad(21)  == ne_out rows 128..202
__global__ void k_xrest(const float* resch, const float* role, const float* misc,
                        const float* dist, float* xr) {
  int idx = blockIdx.x * 256 + threadIdx.x;  // N*96
  int r = idx / 96, c = idx - r * 96;
  float v = 0.f;
  if (c < 6) v = resch[r * 6 + c];
  else if (c < 8) v = role[r * 2 + c - 6];
  else if (c < 11) v = misc[r * 3 + c - 8];
  else if (c < 75) {
    int j = c - 11;
    float d = dist[r * 4 + (j >> 4)];
    float t = d - 0.8f * (float)(j & 15);
    v = __expf(-kGamma * t * t);
  }
  xr[idx] = v;
}

// ---------------- direct-fragment MFMA GEMM (no LDS, no barriers) ----------------
// MODE 0: esm = silu(LN(x_esm @ W + b))           K=1280, N=128
// MODE 1: s0  = silu(LN([esm|xrest] @ W + b))     K=224,  N=128
// MODE 2: [P|Q] = [s|vn] @ B23T (+b1 on Q half)   K=160,  N=256, out bf16 swizzled
// MODE 4: hupd = silu([s|aggS|vnu] @ uw1 + ub1)   K=288,  N=128
struct G2 {
  const float* A1; const float* A2; const float* A3;
  const unsigned short* BT;
  float* out;
  unsigned short* obfP; unsigned short* obfQ;
  const float* bias; const float* lng; const float* lnb;
};

template <int MODE>
__global__ __launch_bounds__(256) void k_gemm2(G2 p) {
  constexpr int K = MODE == 0 ? 1280 : MODE == 1 ? 224 : MODE == 2 ? 160 : 288;
  constexpr int NS = K / 32;
  constexpr int NTC = (MODE == 2) ? 16 : 8;
  const int tid = threadIdx.x, lane = tid & 63, wv = tid >> 6;
  const int g4 = lane >> 4, lc = lane & 15;
  const int r = blockIdx.x * 64 + wv * 16 + lc;   // A-frag row
  const f32x4 z = {0.f, 0.f, 0.f, 0.f};
  f32x4 acc[NTC];
#pragma unroll
  for (int nt = 0; nt < NTC; nt++) acc[nt] = z;

  if constexpr (MODE == 0) {
#pragma unroll 4
    for (int ks = 0; ks < NS; ks++) {
      const int k = ks * 32 + g4 * 8;
      const bf16x8 af = ldA(p.A1 + (size_t)r * 1280 + k);
#pragma unroll
      for (int nt = 0; nt < NTC; nt++)
        acc[nt] = MFMA16(af, *(const bf16x8*)&p.BT[(lc + 16 * nt) * K + k], acc[nt]);
    }
  } else {
#pragma unroll
    for (int ks = 0; ks < NS; ks++) {
      const int k = ks * 32 + g4 * 8;
      const float* ap;
      if constexpr (MODE == 1)
        ap = (k < 128) ? p.A1 + (size_t)r * 128 + k : p.A2 + (size_t)r * 96 + (k - 128);
      else if constexpr (MODE == 2)
        ap = (k < 128) ? p.A1 + (size_t)r * 128 + k : p.A2 + (size_t)r * 32 + (k - 128);
      else
        ap = (k < 128) ? p.A1 + (size_t)r * 128 + k
           : (k < 256) ? p.A2 + (size_t)r * 128 + (k - 128)
                       : p.A3 + (size_t)r * 32 + (k - 256);
      const bf16x8 af = ldA(ap);
#pragma unroll
      for (int nt = 0; nt < NTC; nt++)
        acc[nt] = MFMA16(af, *(const bf16x8*)&p.BT[(lc + 16 * nt) * K + k], acc[nt]);
    }
  }

  const int row0 = blockIdx.x * 64 + wv * 16 + g4 * 4;  // D-frag rows row0..row0+3
  if constexpr (MODE == 0 || MODE == 1) {
    float bias8[8], g8[8], b8[8];
#pragma unroll
    for (int nt = 0; nt < 8; nt++) {
      int c = lc + 16 * nt;
      bias8[nt] = p.bias[c]; g8[nt] = p.lng[c]; b8[nt] = p.lnb[c];
    }
    float rsum[4] = {0.f, 0.f, 0.f, 0.f}, rsq[4] = {0.f, 0.f, 0.f, 0.f};
#pragma unroll
    for (int nt = 0; nt < 8; nt++)
#pragma unroll
      for (int i = 0; i < 4; i++) {
        float x = acc[nt][i] + bias8[nt];
        acc[nt][i] = x; rsum[i] += x; rsq[i] += x * x;
      }
#pragma unroll
    for (int m = 1; m < 16; m <<= 1)
#pragma unroll
      for (int i = 0; i < 4; i++) {
        rsum[i] += __shfl_xor(rsum[i], m);
        rsq[i] += __shfl_xor(rsq[i], m);
      }
#pragma unroll
    for (int i = 0; i < 4; i++) {
      float mu = rsum[i] * (1.f / 128.f);
      float rs = rsqrtf(rsq[i] * (1.f / 128.f) - mu * mu + kLnEps);
#pragma unroll
      for (int nt = 0; nt < 8; nt++) {
        float y = (acc[nt][i] - mu) * rs * g8[nt] + b8[nt];
        p.out[(size_t)(row0 + i) * 128 + lc + 16 * nt] = siluf(y);
      }
    }
  } else if constexpr (MODE == 2) {
#pragma unroll
    for (int i = 0; i < 4; i++) {
      bf16x8 po, qo;
#pragma unroll
      for (int nt = 0; nt < 8; nt++) {
        po[nt] = (short)f2bf(acc[nt][i]);
        qo[nt] = (short)f2bf(acc[nt + 8][i] + p.bias[lc + 16 * nt]);
      }
      *(bf16x8*)&p.obfP[(size_t)(row0 + i) * 128 + lc * 8] = po;
      *(bf16x8*)&p.obfQ[(size_t)(row0 + i) * 128 + lc * 8] = qo;
    }
  } else {
#pragma unroll
    for (int nt = 0; nt < 8; nt++) {
      float bv = p.bias[lc + 16 * nt];
#pragma unroll
      for (int i = 0; i < 4; i++)
        p.out[(size_t)(row0 + i) * 128 + lc + 16 * nt] = siluf(acc[nt][i] + bv);
    }
  }
}

// ---------------- small kernels ----------------
__global__ void k_v0(const float* xv, const float* ivw, float* v) {
  int idx = blockIdx.x * 256 + threadIdx.x;  // < N*48
  int n = idx / 48, f = idx % 48, t = f / 3, i = f - t * 3;
  v[idx] = xv[n * 3 + i] * ivw[t];
}

__global__ void k_vn(const float* v, float* vn) {
  int idx = blockIdx.x * 256 + threadIdx.x;  // < N*32 (padded)
  int n = idx >> 5, t = idx & 31;
  float val = 0.f;
  if (t < 16) {
    const float* b = &v[(size_t)n * 48 + t * 3];
    val = sqrtf(fmaxf(b[0] * b[0] + b[1] * b[1] + b[2] * b[2], 1e-8f));
  }
  vn[idx] = val;
}

// VA/VB in bf16 swizzled layout [n][t*4 + {x,y,z,pad}]
__global__ void k_vab(const float* v, const float* vw,
                      unsigned short* VAb, unsigned short* VBb) {
  int idx = blockIdx.x * 256 + threadIdx.x;  // < N*16
  int n = idx >> 4, t = idx & 15;
  float a0 = 0.f, a1 = 0.f, a2 = 0.f, b0 = 0.f, b1 = 0.f, b2 = 0.f;
#pragma unroll
  for (int c = 0; c < 16; c++) {
    float wa = vw[c * 16 + t], wb = vw[(16 + c) * 16 + t];
    float x0 = v[(size_t)n * 48 + c * 3 + 0];
    float x1 = v[(size_t)n * 48 + c * 3 + 1];
    float x2 = v[(size_t)n * 48 + c * 3 + 2];
    a0 += x0 * wa; a1 += x1 * wa; a2 += x2 * wa;
    b0 += x0 * wb; b1 += x1 * wb; b2 += x2 * wb;
  }
  s16x4 A, Bv;
  A[0] = (short)f2bf(a0); A[1] = (short)f2bf(a1); A[2] = (short)f2bf(a2); A[3] = 0;
  Bv[0] = (short)f2bf(b0); Bv[1] = (short)f2bf(b1); Bv[2] = (short)f2bf(b2); Bv[3] = 0;
  *(s16x4*)&VAb[(size_t)n * 64 + t * 4] = A;
  *(s16x4*)&VBb[(size_t)n * 64 + t * 4] = Bv;
}

// ---------------- CSR build (dst-sorted edge order) ----------------
__global__ void k_hist(const int* ei, int* cnt) {
  int e = blockIdx.x * 256 + threadIdx.x;
  atomicAdd(&cnt[ei[kE + e]], 1);
}

__global__ __launch_bounds__(1024) void k_scan(const int* cnt, int* rowstart, int* cursor) {
  __shared__ int part[1024];
  const int t = threadIdx.x;
  const int base = t * 32;
  int loc[32];
  int s = 0;
#pragma unroll
  for (int i = 0; i < 32; i++) { loc[i] = cnt[base + i]; s += loc[i]; }
  part[t] = s;
  __syncthreads();
  for (int off = 1; off < 1024; off <<= 1) {
    int val = (t >= off) ? part[t - off] : 0;
    __syncthreads();
    part[t] += val;
    __syncthreads();
  }
  int run = (t == 0) ? 0 : part[t - 1];
#pragma unroll
  for (int i = 0; i < 32; i++) {
    rowstart[base + i] = run;
    cursor[base + i] = run;
    run += loc[i];
  }
  if (t == 1023) rowstart[kN] = run;
}

__global__ void k_scatter(const int* ei, const float* pos, int* cursor,
                          int* prm, int* srcp, float* relp, float* lenp) {
  int e = blockIdx.x * 256 + threadIdx.x;
  int a = ei[e], b = ei[kE + e];
  int p = atomicAdd(&cursor[b], 1);
  prm[p] = e;
  srcp[p] = a;
  float dx = pos[(size_t)b * 3 + 0] - pos[(size_t)a * 3 + 0];
  float dy = pos[(size_t)b * 3 + 1] - pos[(size_t)a * 3 + 1];
  float dz = pos[(size_t)b * 3 + 2] - pos[(size_t)a * 3 + 2];
  float n2 = dx * dx + dy * dy + dz * dz;
  float inv = 1.f / sqrtf(fmaxf(n2, 1e-8f));
  float rx = dx * inv, ry = dy * inv, rz = dz * inv;
  relp[(size_t)p * 3 + 0] = rx; relp[(size_t)p * 3 + 1] = ry; relp[(size_t)p * 3 + 2] = rz;
  lenp[p] = sqrtf(fmaxf(rx * rx + ry * ry + rz * rz, 1e-8f));
}

// MFMA edge encoder: wave handles 16 edges; enc(16x32 rbf) @ eew(32x64), LN+silu epilogue.
__global__ __launch_bounds__(256) void k_enc_mfma(
    const int* __restrict__ prm, const float* __restrict__ edr,
    const float* __restrict__ eew, const float* __restrict__ eeb,
    const float* __restrict__ lg, const float* __restrict__ lb,
    __hip_bfloat16* __restrict__ enc) {
  __shared__ unsigned short eewT[64 * 32];  // [col][k] bf16, 4KB
  const int tid = threadIdx.x;
#pragma unroll
  for (int i = 0; i < 8; i++) {
    int idx = tid + i * 256;  // 2048 elems
    int col = idx >> 5, k = idx & 31;
    eewT[col * 32 + k] = f2bf(eew[k * 64 + col]);
  }
  __syncthreads();

  const int lane = tid & 63, wv = tid >> 6;
  const int g4 = lane >> 4, lc = lane & 15;
  const int e0 = blockIdx.x * 64 + wv * 16;

  const int e = prm[e0 + lc];
  const float d = edr[(size_t)e * 2 + (g4 >> 1)];
  const float c0 = 0.8f * (float)((g4 & 1) * 8);
  bf16x8 af;
#pragma unroll
  for (int j = 0; j < 8; j++) {
    float t = d - (c0 + 0.8f * (float)j);
    af[j] = (short)f2bf(__expf(-kGamma * t * t));
  }
  const f32x4 z = {0.f, 0.f, 0.f, 0.f};
  f32x4 acc[4];
#pragma unroll
  for (int ct = 0; ct < 4; ct++)
    acc[ct] = MFMA16(af, *(const bf16x8*)&eewT[(ct * 16 + lc) * 32 + g4 * 8], z);

  float bias4[4], g4v[4], b4[4];
#pragma unroll
  for (int ct = 0; ct < 4; ct++) {
    int col = ct * 16 + lc;
    bias4[ct] = eeb[col]; g4v[ct] = lg[col]; b4[ct] = lb[col];
  }
  float rsum[4] = {0.f, 0.f, 0.f, 0.f}, rsq[4] = {0.f, 0.f, 0.f, 0.f};
#pragma unroll
  for (int ct = 0; ct < 4; ct++)
#pragma unroll
    for (int i = 0; i < 4; i++) {
      float x = acc[ct][i] + bias4[ct];
      acc[ct][i] = x; rsum[i] += x; rsq[i] += x * x;
    }
#pragma unroll
  for (int m = 1; m < 16; m <<= 1)
#pragma unroll
    for (int i = 0; i < 4; i++) {
      rsum[i] += __shfl_xor(rsum[i], m);
      rsq[i] += __shfl_xor(rsq[i], m);
    }
#pragma unroll
  for (int i = 0; i < 4; i++) {
    float mu = rsum[i] * (1.f / 64.f);
    float rs = rsqrtf(rsq[i] * (1.f / 64.f) - mu * mu + kLnEps);
    const size_t row = (size_t)(e0 + g4 * 4 + i);
#pragma unroll
    for (int ct = 0; ct < 4; ct++) {
      float y = (acc[ct][i] - mu) * rs * g4v[ct] + b4[ct];
      enc[row * 64 + ct * 16 + lc] = __float2bfloat16(siluf(y));
    }
  }
}

// ---------------- fused per-dst-node message + in-register aggregation ----------------
// R7 structure; weights read DIRECTLY from pre-transposed global bf16 (L2-resident).
// LDS holds only the per-wave h scratch -> 18.4 KB -> 4 blocks/CU, 8 waves/SIMD.
__global__ __launch_bounds__(512, 8) void k_node_msg(
    const unsigned short* __restrict__ Pb, const unsigned short* __restrict__ Qb,
    const unsigned short* __restrict__ VAb, const unsigned short* __restrict__ VBb,
    const __hip_bfloat16* __restrict__ enc_, const float* __restrict__ relp,
    const float* __restrict__ lenp, const int* __restrict__ srcp,
    const int* __restrict__ rowstart, const float* __restrict__ vglob,
    const unsigned short* __restrict__ we1Tg,   // [128][64]  bf16
    const unsigned short* __restrict__ w2Tg,    // [128][128] bf16
    const unsigned short* __restrict__ w2gwTg,  // [16][128]  bf16
    const float* __restrict__ w1, const float* __restrict__ b2g,
    const float* __restrict__ w2gw, const float* __restrict__ vwg,
    float* __restrict__ aggs, float* __restrict__ aggv, float* __restrict__ vnu) {
  __shared__ unsigned short hS[8][16 * 72];   // 18432 B
  const int tid = threadIdx.x;
  const unsigned short* enc = (const unsigned short*)enc_;

  const int lane = tid & 63, wv = tid >> 6;
  const int g4 = lane >> 4;
  const int lc = lane & 15;
  unsigned short* hrow = &hS[wv][0];

  float wlenR[8], b2R[8];
#pragma unroll
  for (int nt = 0; nt < 8; nt++) {
    int col = lc + 16 * nt;
    wlenR[nt] = w1[320 * 128 + col] + w1[353 * 128 + col];
    b2R[nt] = b2g[col];
  }
  const float gbR = w2gw[2048 + lc];
  const float vwR = vwg[512 + lc];
  const f32x4 z = {0.f, 0.f, 0.f, 0.f};

  for (int n = blockIdx.x * 8 + wv; n < kN; n += gridDim.x * 8) {
    const int r0 = rowstart[n], r1 = rowstart[n + 1];
    float qR[8], vbR[3];
    {
      const bf16x8 qv = *(const bf16x8*)&Qb[(size_t)n * 128 + lc * 8];
#pragma unroll
      for (int nt = 0; nt < 8; nt++) qR[nt] = b2f((unsigned short)qv[nt]);
      const s16x4 vbv = *(const s16x4*)&VBb[(size_t)n * 64 + lc * 4];
#pragma unroll
      for (int j = 0; j < 3; j++) vbR[j] = b2f((unsigned short)vbv[j]);
    }
    float colsum[8];
#pragma unroll
    for (int nt = 0; nt < 8; nt++) colsum[nt] = 0.f;
    float av0 = 0.f, av1 = 0.f, av2 = 0.f;

    for (int base = r0; base < r1; base += 16) {
      int nv = r1 - base; if (nv > 16) nv = 16;

      int pa = base + lc; if (pa >= kE) pa = kE - 1;
      const bf16x8 a0 = *(const bf16x8*)&enc[(size_t)pa * 64 + g4 * 8];
      const bf16x8 a1 = *(const bf16x8*)&enc[(size_t)pa * 64 + 32 + g4 * 8];
      f32x4 acc[8];
#pragma unroll
      for (int nt = 0; nt < 8; nt++) {
        acc[nt] = MFMA16(a0, *(const bf16x8*)&we1Tg[(lc + 16 * nt) * 64 + g4 * 8], z);
        acc[nt] = MFMA16(a1, *(const bf16x8*)&we1Tg[(lc + 16 * nt) * 64 + 32 + g4 * 8], acc[nt]);
      }

      int sn[4], pr[4]; float le[4];
#pragma unroll
      for (int i = 0; i < 4; i++) {
        int p = base + g4 * 4 + i; if (p >= kE) p = kE - 1;
        pr[i] = p; sn[i] = srcp[p]; le[i] = lenp[p];
      }
      // P[src] gather: one 16B load per edge per lane (swizzled bf16 row)
#pragma unroll
      for (int i = 0; i < 4; i++) {
        const bf16x8 pbv = *(const bf16x8*)&Pb[(size_t)sn[i] * 128 + lc * 8];
#pragma unroll
        for (int nt = 0; nt < 8; nt++)
          acc[nt][i] += b2f((unsigned short)pbv[nt]) + qR[nt] + le[i] * wlenR[nt];
      }

      // stage B two-pass: m = silu(h)(16x128) @ w2 + b2; gate fused via w2@gw
      f32x4 m[8]; f32x4 gac;
#pragma unroll
      for (int i = 0; i < 4; i++)
#pragma unroll
        for (int nt = 0; nt < 4; nt++)
          hrow[(g4 * 4 + i) * 72 + lc + 16 * nt] = f2bf(siluf(acc[nt][i]));
      {
        const bf16x8 aB0 = *(const bf16x8*)&hrow[lc * 72 + g4 * 8];
        const bf16x8 aB1 = *(const bf16x8*)&hrow[lc * 72 + 32 + g4 * 8];
#pragma unroll
        for (int nt = 0; nt < 8; nt++) {
          m[nt] = MFMA16(aB0, *(const bf16x8*)&w2Tg[(lc + 16 * nt) * 128 + g4 * 8], z);
          m[nt] = MFMA16(aB1, *(const bf16x8*)&w2Tg[(lc + 16 * nt) * 128 + 32 + g4 * 8], m[nt]);
        }
        gac = MFMA16(aB0, *(const bf16x8*)&w2gwTg[lc * 128 + g4 * 8], z);
        gac = MFMA16(aB1, *(const bf16x8*)&w2gwTg[lc * 128 + 32 + g4 * 8], gac);
      }
#pragma unroll
      for (int i = 0; i < 4; i++)
#pragma unroll
        for (int nt = 4; nt < 8; nt++)
          hrow[(g4 * 4 + i) * 72 + lc + 16 * (nt - 4)] = f2bf(siluf(acc[nt][i]));
      {
        const bf16x8 aB2 = *(const bf16x8*)&hrow[lc * 72 + g4 * 8];
        const bf16x8 aB3 = *(const bf16x8*)&hrow[lc * 72 + 32 + g4 * 8];
#pragma unroll
        for (int nt = 0; nt < 8; nt++) {
          m[nt] = MFMA16(aB2, *(const bf16x8*)&w2Tg[(lc + 16 * nt) * 128 + 64 + g4 * 8], m[nt]);
          m[nt] = MFMA16(aB3, *(const bf16x8*)&w2Tg[(lc + 16 * nt) * 128 + 96 + g4 * 8], m[nt]);
        }
        gac = MFMA16(aB2, *(const bf16x8*)&w2gwTg[lc * 128 + 64 + g4 * 8], gac);
        gac = MFMA16(aB3, *(const bf16x8*)&w2gwTg[lc * 128 + 96 + g4 * 8], gac);
      }
#pragma unroll
      for (int nt = 0; nt < 8; nt++) {
#pragma unroll
        for (int i = 0; i < 4; i++) m[nt][i] += b2R[nt];
      }

      // accumulate valid rows in registers
#pragma unroll
      for (int i = 0; i < 4; i++) {
        const int row = g4 * 4 + i;
        if (row < nv) {
#pragma unroll
          for (int nt = 0; nt < 8; nt++) colsum[nt] += m[nt][i];
          float g = sigmf(gac[i] + gbR);
          const s16x4 vav = *(const s16x4*)&VAb[(size_t)sn[i] * 64 + lc * 4];
          const float* rp = &relp[(size_t)pr[i] * 3];
          av0 += g * (b2f((unsigned short)vav[0]) + vbR[0] + rp[0] * vwR);
          av1 += g * (b2f((unsigned short)vav[1]) + vbR[1] + rp[1] * vwR);
          av2 += g * (b2f((unsigned short)vav[2]) + vbR[2] + rp[2] * vwR);
        }
      }
    }

#pragma unroll
    for (int nt = 0; nt < 8; nt++) {
      colsum[nt] += __shfl_xor(colsum[nt], 16);
      colsum[nt] += __shfl_xor(colsum[nt], 32);
    }
    av0 += __shfl_xor(av0, 16); av0 += __shfl_xor(av0, 32);
    av1 += __shfl_xor(av1, 16); av1 += __shfl_xor(av1, 32);
    av2 += __shfl_xor(av2, 16); av2 += __shfl_xor(av2, 32);

    if (g4 == 0) {
#pragma unroll
      for (int nt = 0; nt < 8; nt++) aggs[(size_t)n * 128 + lc + 16 * nt] = colsum[nt];
      aggv[(size_t)n * 48 + lc * 3 + 0] = av0;
      aggv[(size_t)n * 48 + lc * 3 + 1] = av1;
      aggv[(size_t)n * 48 + lc * 3 + 2] = av2;
      vnu[(size_t)n * 32 + 16 + lc] = sqrtf(fmaxf(av0 * av0 + av1 * av1 + av2 * av2, 1e-8f));
    } else if (g4 == 1) {
      float x0 = vglob[(size_t)n * 48 + lc * 3 + 0];
      float x1 = vglob[(size_t)n * 48 + lc * 3 + 1];
      float x2 = vglob[(size_t)n * 48 + lc * 3 + 2];
      vnu[(size_t)n * 32 + lc] = sqrtf(fmaxf(x0 * x0 + x1 * x1 + x2 * x2, 1e-8f));
    }
  }
}

// ---------------- node update stage 2 (direct-frag GEMM, gate, v+=, s=LN(s+ds), vn out) ----
__global__ __launch_bounds__(256) void k_upd2(
    const float* __restrict__ hupd, const unsigned short* __restrict__ BuT,
    const float* __restrict__ b2,
    const float* __restrict__ ugw, const float* __restrict__ ugb, const float* __restrict__ uvw,
    const float* __restrict__ aggv, const float* __restrict__ lng, const float* __restrict__ lnb,
    float* __restrict__ s, float* __restrict__ v, float* __restrict__ vnout) {
  __shared__ __align__(16) float dsb[64 * 129];
  __shared__ float smu[64], srs[64];
  __shared__ float uvwS[512];
  const int tid = threadIdx.x;
  const int bm = blockIdx.x * 64;
  const int lane = tid & 63, wv = tid >> 6;
  const int g4 = lane >> 4, lc = lane & 15;
  uvwS[tid] = uvw[tid]; uvwS[tid + 256] = uvw[tid + 256];
  const f32x4 z = {0.f, 0.f, 0.f, 0.f};
  const int r = bm + wv * 16 + lc;
  f32x4 acc[8];
#pragma unroll
  for (int nt = 0; nt < 8; nt++) acc[nt] = z;

#pragma unroll
  for (int ks = 0; ks < 4; ks++) {
    const int k = ks * 32 + g4 * 8;
    const bf16x8 af = ldA(hupd + (size_t)r * 128 + k);
#pragma unroll
    for (int nt = 0; nt < 8; nt++)
      acc[nt] = MFMA16(af, *(const bf16x8*)&BuT[(lc + 16 * nt) * 128 + k], acc[nt]);
  }
#pragma unroll
  for (int nt = 0; nt < 8; nt++) {
    float bv = b2[lc + 16 * nt];
#pragma unroll
    for (int i = 0; i < 4; i++)
      dsb[(wv * 16 + g4 * 4 + i) * 129 + lc + 16 * nt] = acc[nt][i] + bv;
  }
  __syncthreads();

  const int rr = tid >> 2, p = tid & 3;
  const int n = bm + rr;
  float g[4];
#pragma unroll
  for (int j = 0; j < 4; j++) g[j] = ugb[p * 4 + j];
#pragma unroll 8
  for (int k = 0; k < 128; k++) {
    float m = dsb[rr * 129 + k];
    const float4 wg = *(const float4*)&ugw[k * 16 + p * 4];
    g[0] += m * wg.x; g[1] += m * wg.y; g[2] += m * wg.z; g[3] += m * wg.w;
  }
#pragma unroll
  for (int j = 0; j < 4; j++) g[j] = sigmf(g[j]);

  float vnew[12];
#pragma unroll
  for (int i2 = 0; i2 < 3; i2++) {
    float xv[16], xa[16];
#pragma unroll
    for (int c = 0; c < 16; c++) {
      xv[c] = v[(size_t)n * 48 + c * 3 + i2];
      xa[c] = aggv[(size_t)n * 48 + c * 3 + i2];
    }
#pragma unroll
    for (int j = 0; j < 4; j++) {
      int t = p * 4 + j;
      float a = 0.f;
#pragma unroll
      for (int c = 0; c < 16; c++)
        a += xv[c] * uvwS[c * 16 + t] + xa[c] * uvwS[(16 + c) * 16 + t];
      vnew[j * 3 + i2] = xv[t] + a * g[j];
    }
  }
  if (tid < 64) {
    float sm = 0.f, sq = 0.f;
    for (int c = 0; c < 128; c++) {
      float x = s[(size_t)(bm + tid) * 128 + c] + dsb[tid * 129 + c];
      sm += x; sq += x * x;
    }
    float mu = sm * (1.f / 128.f);
    float var = sq * (1.f / 128.f) - mu * mu;
    smu[tid] = mu; srs[tid] = rsqrtf(var + kLnEps);
  }
  __syncthreads();
#pragma unroll
  for (int j = 0; j < 4; j++) {
    float n0 = vnew[j * 3 + 0], n1 = vnew[j * 3 + 1], n2 = vnew[j * 3 + 2];
#pragma unroll
    for (int i2 = 0; i2 < 3; i2++)
      v[(size_t)n * 48 + (p * 4 + j) * 3 + i2] = vnew[j * 3 + i2];
    vnout[(size_t)n * 32 + p * 4 + j] = sqrtf(fmaxf(n0 * n0 + n1 * n1 + n2 * n2, 1e-8f));
    vnout[(size_t)n * 32 + 16 + p * 4 + j] = 0.f;
  }
#pragma unroll 4
  for (int i = 0; i < 32; i++) {
    int idx = tid + i * 256; int rw = idx >> 7, c = idx & 127;
    float x = s[(size_t)(bm + rw) * 128 + c] + dsb[rw * 129 + c];
    float y = (x - smu[rw]) * srs[rw] * lng[c] + lnb[c];
    s[(size_t)(bm + rw) * 128 + c] = y;
  }
}

// ---------------- pooling + heads ----------------
DI int lbound(const int* b, int nn, int key) {
  int lo = 0, hi = nn;
  while (lo < hi) { int m = (lo + hi) >> 1; if (b[m] < key) lo = m + 1; else hi = m; }
  return lo;
}

__global__ void k_pool(const float* s, const int* batch, float* dout) {
  int g = blockIdx.x, tid = threadIdx.x;  // 128 threads
  int lo = lbound(batch, kN, g), hi = lbound(batch, kN, g + 1);
  float sum = 0.f, mx = -3.402823e38f;
  for (int n = lo; n < hi; n++) {
    float x = s[(size_t)n * 128 + tid];
    sum += x; mx = fmaxf(mx, x);
  }
  int cnt = hi - lo;
  float mean = sum / fmaxf((float)cnt, 1.f);
  if (cnt == 0) mx = 0.f;
  dout[960 + g * 256 + tid] = mean;
  dout[960 + g * 256 + 128 + tid] = mx;
}

__global__ void k_heads(const float* hw1, const float* hb1, const float* hw2, const float* hb2,
                        const float* ew1, const float* eb1, const float* ew2, const float* eb2,
                        float* dout) {
  __shared__ float emb[256], h1[256];
  int g = blockIdx.x, tid = threadIdx.x;  // 128 threads
  emb[tid] = dout[960 + g * 256 + tid];
  emb[128 + tid] = dout[960 + g * 256 + 128 + tid];
  __syncthreads();
  float am = hb1[tid], ae = eb1[tid];
#pragma unroll 4
  for (int k = 0; k < 256; k++) {
    float e = emb[k];
    am += e * hw1[k * 128 + tid];
    ae += e * ew1[k * 128 + tid];
  }
  h1[tid] = siluf(am); h1[128 + tid] = siluf(ae);
  __syncthreads();
  if (tid < 8) {
    float a = hb2[tid];
    for (int j = 0; j < 128; j++) a += h1[j] * hw2[j * 8 + tid];
    dout[g * 8 + tid] = a;
  } else if (tid >= 64 && tid < 71) {
    int o = tid - 64;
    float a = eb2[o];
    for (int j = 0; j < 128; j++) a += h1[128 + j] * ew2[j * 7 + o];
    dout[512 + g * 7 + o] = a;
  }
}

// ---------------- launcher ----------------
extern "C" void kernel_launch(void* const* d_in, const int* in_sizes, int n_in,
                              void* d_out, int out_size, void* d_ws, size_t ws_size,
                              hipStream_t stream) {
  (void)in_sizes; (void)n_in; (void)out_size; (void)ws_size;
  const float* x_esm   = (const float*)d_in[0];
  const float* x_resch = (const float*)d_in[1];
  const float* x_role  = (const float*)d_in[2];
  const float* x_dist  = (const float*)d_in[3];
  const float* x_misc  = (const float*)d_in[4];
  const float* x_vec   = (const float*)d_in[5];
  const float* pos     = (const float*)d_in[6];
  const float* edr     = (const float*)d_in[7];
  const float* ne_esm_w = (const float*)d_in[8];
  const float* ne_esm_b = (const float*)d_in[9];
  const float* ne_esm_lg = (const float*)d_in[10];
  const float* ne_esm_lb = (const float*)d_in[11];
  const float* ne_out_w = (const float*)d_in[12];
  const float* ne_out_b = (const float*)d_in[13];
  const float* ne_out_lg = (const float*)d_in[14];
  const float* ne_out_lb = (const float*)d_in[15];
  const float* ee_w = (const float*)d_in[16];
  const float* ee_b = (const float*)d_in[17];
  const float* ee_lg = (const float*)d_in[18];
  const float* ee_lb = (const float*)d_in[19];
  const float* ivw = (const float*)d_in[20];
  const float* msg_w1 = (const float*)d_in[21];
  const float* msg_b1 = (const float*)d_in[22];
  const float* msg_w2 = (const float*)d_in[23];
  const float* msg_b2 = (const float*)d_in[24];
  const float* msg_vw = (const float*)d_in[25];
  const float* msg_gw = (const float*)d_in[26];
  const float* msg_gb = (const float*)d_in[27];
  const float* upd_w1 = (const float*)d_in[28];
  const float* upd_b1 = (const float*)d_in[29];
  const float* upd_w2 = (const float*)d_in[30];
  const float* upd_b2 = (const float*)d_in[31];
  const float* upd_vw = (const float*)d_in[32];
  const float* upd_gw = (const float*)d_in[33];
  const float* upd_gb = (const float*)d_in[34];
  const float* ln_g = (const float*)d_in[35];
  const float* ln_b = (const float*)d_in[36];
  const float* hm_w1 = (const float*)d_in[37];
  const float* hm_b1 = (const float*)d_in[38];
  const float* hm_w2 = (const float*)d_in[39];
  const float* hm_b2 = (const float*)d_in[40];
  const float* he_w1 = (const float*)d_in[41];
  const float* he_b1 = (const float*)d_in[42];
  const float* he_w2 = (const float*)d_in[43];
  const float* he_b2 = (const float*)d_in[44];
  const int* ei = (const int*)d_in[45];
  const int* batch = (const int*)d_in[46];
  float* dout = (float*)d_out;

  // workspace layout
  size_t off = 0;
  auto alloc = [&](size_t bytes) {
    void* p = (char*)d_ws + off;
    off += (bytes + 255) & ~(size_t)255;
    return p;
  };
  float* s    = (float*)alloc((size_t)kN * 128 * 4);
  float* v    = (float*)alloc((size_t)kN * 48 * 4);
  float* vn   = (float*)alloc((size_t)kN * 32 * 4);      // padded to 32
  unsigned short* Pb = (unsigned short*)alloc((size_t)kN * 128 * 2);
  unsigned short* Qb = (unsigned short*)alloc((size_t)kN * 128 * 2);
  unsigned short* VAb = (unsigned short*)alloc((size_t)kN * 64 * 2);
  unsigned short* VBb = (unsigned short*)alloc((size_t)kN * 64 * 2);
  float* aggS = (float*)alloc((size_t)kN * 128 * 4);
  float* aggV = (float*)alloc((size_t)kN * 48 * 4);
  float* vnu  = (float*)alloc((size_t)kN * 32 * 4);
  float* hupd = (float*)alloc((size_t)kN * 128 * 4);     // also esm (pre-layers)
  float* xrest = (float*)alloc((size_t)kN * 96 * 4);
  __hip_bfloat16* enc = (__hip_bfloat16*)alloc((size_t)kE * 64 * 2);
  float* relp = (float*)alloc((size_t)kE * 3 * 4);
  float* lenp = (float*)alloc((size_t)kE * 4);
  int* srcp   = (int*)alloc((size_t)kE * 4);
  int* prm    = (int*)alloc((size_t)kE * 4);
  int* cnt    = (int*)alloc((size_t)kN * 4);
  int* rowstart = (int*)alloc((size_t)(kN + 1) * 4);
  int* cursor = (int*)alloc((size_t)kN * 4);
  unsigned short* B0T = (unsigned short*)alloc((size_t)128 * 1280 * 2);
  unsigned short* B1T = (unsigned short*)alloc((size_t)128 * 224 * 2);
  unsigned short* B23T = (unsigned short*)alloc((size_t)kL * 256 * 160 * 2);
  unsigned short* B4T = (unsigned short*)alloc((size_t)kL * 128 * 288 * 2);
  unsigned short* BuT = (unsigned short*)alloc((size_t)kL * 128 * 128 * 2);
  unsigned short* we1Tg = (unsigned short*)alloc((size_t)kL * 128 * 64 * 2);
  unsigned short* w2Tg  = (unsigned short*)alloc((size_t)kL * 128 * 128 * 2);
  unsigned short* w2gwTg = (unsigned short*)alloc((size_t)kL * 16 * 128 * 2);
  float* w2gwL = (float*)alloc((size_t)kL * 2064 * 4);
  float* esm = hupd;

  // ---- one-time: CSR build, B^T weights, composed gate weights, feature blocks ----
  hipMemsetAsync(cnt, 0, (size_t)kN * 4, stream);
  k_hist<<<kE / 256, 256, 0, stream>>>(ei, cnt);
  k_scan<<<1, 1024, 0, stream>>>(cnt, rowstart, cursor);
  k_scatter<<<kE / 256, 256, 0, stream>>>(ei, pos, cursor, prm, srcp, relp, lenp);
  k_enc_mfma<<<kE / 64, 256, 0, stream>>>(prm, edr, ee_w, ee_b, ee_lg, ee_lb, enc);
  k_btA<<<(1280 * 128 + 255) / 256, 256, 0, stream>>>(ne_esm_w, B0T, 1280);
  k_bt1<<<(224 * 128 + 255) / 256, 256, 0, stream>>>(ne_out_w, B1T);
  k_xrest<<<(kN * 96 + 255) / 256, 256, 0, stream>>>(x_resch, x_role, x_misc, x_dist, xrest);
  for (int l = 0; l < kL; l++) {
    k_btPQ<<<(256 * 160 + 255) / 256, 256, 0, stream>>>(msg_w1 + (size_t)l * 354 * 128,
                                                        B23T + (size_t)l * 256 * 160);
    k_btA<<<(288 * 128 + 255) / 256, 256, 0, stream>>>(upd_w1 + (size_t)l * 288 * 128,
                                                       B4T + (size_t)l * 128 * 288, 288);
    k_btA<<<(128 * 128 + 255) / 256, 256, 0, stream>>>(upd_w2 + (size_t)l * 128 * 128,
                                                       BuT + (size_t)l * 128 * 128, 128);
    k_btA<<<(64 * 128 + 255) / 256, 256, 0, stream>>>(msg_w1 + (size_t)l * 354 * 128 + 256 * 128,
                                                      we1Tg + (size_t)l * 128 * 64, 64);
    k_btA<<<(128 * 128 + 255) / 256, 256, 0, stream>>>(msg_w2 + (size_t)l * 128 * 128,
                                                       w2Tg + (size_t)l * 128 * 128, 128);
    k_w2gw<<<9, 256, 0, stream>>>(msg_w2 + (size_t)l * 128 * 128, msg_gw + l * 128 * 16,
                                  msg_b2 + l * 128, msg_gb + l * 16, w2gwL + (size_t)l * 2064);
    k_gwT<<<8, 256, 0, stream>>>(w2gwL + (size_t)l * 2064, w2gwTg + (size_t)l * 16 * 128);
  }

  // ---- encoders ----
  {
    G2 p{}; p.A1 = x_esm; p.BT = B0T; p.out = esm;
    p.bias = ne_esm_b; p.lng = ne_esm_lg; p.lnb = ne_esm_lb;
    k_gemm2<0><<<kN / 64, 256, 0, stream>>>(p);
  }
  {
    G2 p{}; p.A1 = esm; p.A2 = xrest; p.BT = B1T; p.out = s;
    p.bias = ne_out_b; p.lng = ne_out_lg; p.lnb = ne_out_lb;
    k_gemm2<1><<<kN / 64, 256, 0, stream>>>(p);
  }
  k_v0<<<kN * 48 / 256, 256, 0, stream>>>(x_vec, ivw, v);
  k_vn<<<kN * 32 / 256, 256, 0, stream>>>(v, vn);

  // ---- message passing layers ----
  for (int l = 0; l < kL; l++) {
    const float* w1l = msg_w1 + (size_t)l * 354 * 128;
    const float* b1l = msg_b1 + l * 128;
    const float* b2l = msg_b2 + l * 128;
    const float* vwl = msg_vw + l * 33 * 16;
    const float* ub1 = upd_b1 + l * 128;
    const float* ub2 = upd_b2 + l * 128;
    const float* uvwl = upd_vw + l * 32 * 16;
    const float* ugwl = upd_gw + l * 128 * 16;
    const float* ugbl = upd_gb + l * 16;
    const float* lgl = ln_g + l * 128;
    const float* lbl = ln_b + l * 128;

    {
      G2 p{}; p.A1 = s; p.A2 = vn; p.BT = B23T + (size_t)l * 256 * 160;
      p.obfP = Pb; p.obfQ = Qb; p.bias = b1l;
      k_gemm2<2><<<kN / 64, 256, 0, stream>>>(p);
    }
    k_vab<<<kN * 16 / 256, 256, 0, stream>>>(v, vwl, VAb, VBb);
    k_node_msg<<<1024, 512, 0, stream>>>(Pb, Qb, VAb, VBb, enc, relp, lenp, srcp,
                                         rowstart, v,
                                         we1Tg + (size_t)l * 128 * 64,
                                         w2Tg + (size_t)l * 128 * 128,
                                         w2gwTg + (size_t)l * 16 * 128,
                                         w1l, b2l, w2gwL + (size_t)l * 2064, vwl,
                                         aggS, aggV, vnu);
    {
      G2 p{}; p.A1 = s; p.A2 = aggS; p.A3 = vnu; p.BT = B4T + (size_t)l * 128 * 288;
      p.out = hupd; p.bias = ub1;
      k_gemm2<4><<<kN / 64, 256, 0, stream>>>(p);
    }
    k_upd2<<<kN / 64, 256, 0, stream>>>(hupd, BuT + (size_t)l * 128 * 128, ub2,
                                        ugwl, ugbl, uvwl, aggV, lgl, lbl, s, v, vn);
  }

  // ---- pooling + heads ----
  k_pool<<<kB, 128, 0, stream>>>(s, batch, dout);
  k_heads<<<kB, 128, 0, stream>>>(hm_w1, hm_b1, hm_w2, hm_b2,
                                  he_w1, he_b1, he_w2, he_b2, dout);
}

// Round 10
// 1668.981 us; speedup vs baseline: 4.8729x; 4.8729x over previous
//
#include <hip/hip_runtime.h>
#include <hip/hip_bf16.h>
#include <cstddef>

// ---------------- problem constants ----------------
constexpr int kN = 32768;          // nodes
constexpr int kE = 524288;         // edges
constexpr int kB = 64;             // graphs
constexpr int kL = 4;              // layers
constexpr float kGamma = (float)(1.0 / (0.5625 + 1e-8));  // 1/((12/16)^2+1e-8)
constexpr float kLnEps = 1e-5f;

#define DI __device__ __forceinline__

typedef __attribute__((ext_vector_type(8))) short bf16x8;
typedef __attribute__((ext_vector_type(4))) short s16x4;
typedef __attribute__((ext_vector_type(4))) float f32x4;
#define MFMA16(a, b, c) __builtin_amdgcn_mfma_f32_16x16x32_bf16(a, b, c, 0, 0, 0)

DI float siluf(float x) { return x / (1.f + __expf(-x)); }
DI float sigmf(float x) { return 1.f / (1.f + __expf(-x)); }
DI unsigned short f2bf(float x) {
  __hip_bfloat16 b = __float2bfloat16(x);
  return *(unsigned short*)&b;
}
DI float b2f(unsigned short u) {
  union { unsigned i; float f; } c; c.i = ((unsigned)u) << 16; return c.f;
}
// load 8 consecutive fp32, convert to a bf16x8 A/B fragment
DI bf16x8 ldA(const float* p) {
  const float4 a = *(const float4*)p;
  const float4 b = *(const float4*)(p + 4);
  bf16x8 r;
  r[0] = (short)f2bf(a.x); r[1] = (short)f2bf(a.y);
  r[2] = (short)f2bf(a.z); r[3] = (short)f2bf(a.w);
  r[4] = (short)f2bf(b.x); r[5] = (short)f2bf(b.y);
  r[6] = (short)f2bf(b.z); r[7] = (short)f2bf(b.w);
  return r;
}

// ---------------- B^T builder kernels (bf16, [col][k], row stride K) ----------------
__global__ void k_btA(const float* src, unsigned short* dst, int K) {
  int idx = blockIdx.x * 256 + threadIdx.x;  // K*128 threads; src is [K][128]
  if (idx >= K * 128) return;
  int c = idx & 127, k = idx >> 7;
  dst[c * K + k] = f2bf(src[(size_t)k * 128 + c]);
}

__global__ void k_bt1(const float* w, unsigned short* dst) {
  int idx = blockIdx.x * 256 + threadIdx.x;  // 128*224
  int c = idx & 127, k = idx >> 7;
  dst[c * 224 + k] = f2bf(k < 203 ? w[(size_t)k * 128 + c] : 0.f);
}

__global__ void k_btPQ(const float* w1, unsigned short* dst) {
  int idx = blockIdx.x * 256 + threadIdx.x;  // 256*160
  int cc = idx / 160, k = idx - cc * 160;
  int c = cc & 127, half = cc >> 7;
  float v = 0.f;
  if (k < 128) v = w1[(size_t)(half * 128 + k) * 128 + c];
  else if (k < 144) v = w1[(size_t)(321 + half * 16 + (k - 128)) * 128 + c];
  dst[idx] = f2bf(v);
}

// w2gw[k][t] = sum_j w2[k][j]*gw[j][t]; [2048..2063]: gb2[t] = gb[t] + sum_j b2[j]*gw[j][t]
__global__ void k_w2gw(const float* w2, const float* gw, const float* b2, const float* gb,
                       float* out) {
  int idx = blockIdx.x * 256 + threadIdx.x;
  if (idx < 2048) {
    int k = idx >> 4, t = idx & 15;
    float a = 0.f;
    for (int j = 0; j < 128; j++) a += w2[(size_t)k * 128 + j] * gw[j * 16 + t];
    out[idx] = a;
  } else if (idx < 2064) {
    int t = idx - 2048;
    float a = gb[t];
    for (int j = 0; j < 128; j++) a += b2[j] * gw[j * 16 + t];
    out[idx] = a;
  }
}

// xrest[N][96]: reschem(6)|role(2)|misc(3)|rbf(64)|pad(21)  == ne_out rows 128..202
__global__ void k_xrest(const float* resch, const float* role, const float* misc,
                        const float* dist, float* xr) {
  int idx = blockIdx.x * 256 + threadIdx.x;  // N*96
  int r = idx / 96, c = idx - r * 96;
  float v = 0.f;
  if (c < 6) v = resch[r * 6 + c];
  else if (c < 8) v = role[r * 2 + c - 6];
  else if (c < 11) v = misc[r * 3 + c - 8];
  else if (c < 75) {
    int j = c - 11;
    float d = dist[r * 4 + (j >> 4)];
    float t = d - 0.8f * (float)(j & 15);
    v = __expf(-kGamma * t * t);
  }
  xr[idx] = v;
}

// ---------------- direct-fragment MFMA GEMM (no LDS, no barriers) ----------------
// MODE 0: esm = silu(LN(x_esm @ W + b))           K=1280, N=128
// MODE 1: s0  = silu(LN([esm|xrest] @ W + b))     K=224,  N=128
// MODE 2: [P|Q] = [s|vn] @ B23T (+b1 on Q half)   K=160,  N=256, out bf16 swizzled
struct G2 {
  const float* A1; const float* A2; const float* A3;
  const unsigned short* BT;
  float* out;
  unsigned short* obfP; unsigned short* obfQ;
  const float* bias; const float* lng; const float* lnb;
};

template <int MODE>
__global__ __launch_bounds__(256) void k_gemm2(G2 p) {
  constexpr int K = MODE == 0 ? 1280 : MODE == 1 ? 224 : 160;
  constexpr int NS = K / 32;
  constexpr int NTC = (MODE == 2) ? 16 : 8;
  const int tid = threadIdx.x, lane = tid & 63, wv = tid >> 6;
  const int g4 = lane >> 4, lc = lane & 15;
  const int r = blockIdx.x * 64 + wv * 16 + lc;   // A-frag row
  const f32x4 z = {0.f, 0.f, 0.f, 0.f};
  f32x4 acc[NTC];
#pragma unroll
  for (int nt = 0; nt < NTC; nt++) acc[nt] = z;

  if constexpr (MODE == 0) {
#pragma unroll 4
    for (int ks = 0; ks < NS; ks++) {
      const int k = ks * 32 + g4 * 8;
      const bf16x8 af = ldA(p.A1 + (size_t)r * 1280 + k);
#pragma unroll
      for (int nt = 0; nt < NTC; nt++)
        acc[nt] = MFMA16(af, *(const bf16x8*)&p.BT[(lc + 16 * nt) * K + k], acc[nt]);
    }
  } else {
#pragma unroll
    for (int ks = 0; ks < NS; ks++) {
      const int k = ks * 32 + g4 * 8;
      const float* ap;
      if constexpr (MODE == 1)
        ap = (k < 128) ? p.A1 + (size_t)r * 128 + k : p.A2 + (size_t)r * 96 + (k - 128);
      else
        ap = (k < 128) ? p.A1 + (size_t)r * 128 + k : p.A2 + (size_t)r * 32 + (k - 128);
      const bf16x8 af = ldA(ap);
#pragma unroll
      for (int nt = 0; nt < NTC; nt++)
        acc[nt] = MFMA16(af, *(const bf16x8*)&p.BT[(lc + 16 * nt) * K + k], acc[nt]);
    }
  }

  const int row0 = blockIdx.x * 64 + wv * 16 + g4 * 4;  // D-frag rows row0..row0+3
  if constexpr (MODE == 0 || MODE == 1) {
    float bias8[8], g8[8], b8[8];
#pragma unroll
    for (int nt = 0; nt < 8; nt++) {
      int c = lc + 16 * nt;
      bias8[nt] = p.bias[c]; g8[nt] = p.lng[c]; b8[nt] = p.lnb[c];
    }
    float rsum[4] = {0.f, 0.f, 0.f, 0.f}, rsq[4] = {0.f, 0.f, 0.f, 0.f};
#pragma unroll
    for (int nt = 0; nt < 8; nt++)
#pragma unroll
      for (int i = 0; i < 4; i++) {
        float x = acc[nt][i] + bias8[nt];
        acc[nt][i] = x; rsum[i] += x; rsq[i] += x * x;
      }
#pragma unroll
    for (int m = 1; m < 16; m <<= 1)
#pragma unroll
      for (int i = 0; i < 4; i++) {
        rsum[i] += __shfl_xor(rsum[i], m);
        rsq[i] += __shfl_xor(rsq[i], m);
      }
#pragma unroll
    for (int i = 0; i < 4; i++) {
      float mu = rsum[i] * (1.f / 128.f);
      float rs = rsqrtf(rsq[i] * (1.f / 128.f) - mu * mu + kLnEps);
#pragma unroll
      for (int nt = 0; nt < 8; nt++) {
        float y = (acc[nt][i] - mu) * rs * g8[nt] + b8[nt];
        p.out[(size_t)(row0 + i) * 128 + lc + 16 * nt] = siluf(y);
      }
    }
  } else {
#pragma unroll
    for (int i = 0; i < 4; i++) {
      bf16x8 po, qo;
#pragma unroll
      for (int nt = 0; nt < 8; nt++) {
        po[nt] = (short)f2bf(acc[nt][i]);
        qo[nt] = (short)f2bf(acc[nt + 8][i] + p.bias[lc + 16 * nt]);
      }
      *(bf16x8*)&p.obfP[(size_t)(row0 + i) * 128 + lc * 8] = po;
      *(bf16x8*)&p.obfQ[(size_t)(row0 + i) * 128 + lc * 8] = qo;
    }
  }
}

// ---------------- small kernels ----------------
__global__ void k_v0(const float* xv, const float* ivw, float* v) {
  int idx = blockIdx.x * 256 + threadIdx.x;  // < N*48
  int n = idx / 48, f = idx % 48, t = f / 3, i = f - t * 3;
  v[idx] = xv[n * 3 + i] * ivw[t];
}

__global__ void k_vn(const float* v, float* vn) {
  int idx = blockIdx.x * 256 + threadIdx.x;  // < N*32 (padded)
  int n = idx >> 5, t = idx & 31;
  float val = 0.f;
  if (t < 16) {
    const float* b = &v[(size_t)n * 48 + t * 3];
    val = sqrtf(fmaxf(b[0] * b[0] + b[1] * b[1] + b[2] * b[2], 1e-8f));
  }
  vn[idx] = val;
}

// VA/VB in bf16 swizzled layout [n][t*4 + {x,y,z,pad}]
__global__ void k_vab(const float* v, const float* vw,
                      unsigned short* VAb, unsigned short* VBb) {
  int idx = blockIdx.x * 256 + threadIdx.x;  // < N*16
  int n = idx >> 4, t = idx & 15;
  float a0 = 0.f, a1 = 0.f, a2 = 0.f, b0 = 0.f, b1 = 0.f, b2 = 0.f;
#pragma unroll
  for (int c = 0; c < 16; c++) {
    float wa = vw[c * 16 + t], wb = vw[(16 + c) * 16 + t];
    float x0 = v[(size_t)n * 48 + c * 3 + 0];
    float x1 = v[(size_t)n * 48 + c * 3 + 1];
    float x2 = v[(size_t)n * 48 + c * 3 + 2];
    a0 += x0 * wa; a1 += x1 * wa; a2 += x2 * wa;
    b0 += x0 * wb; b1 += x1 * wb; b2 += x2 * wb;
  }
  s16x4 A, Bv;
  A[0] = (short)f2bf(a0); A[1] = (short)f2bf(a1); A[2] = (short)f2bf(a2); A[3] = 0;
  Bv[0] = (short)f2bf(b0); Bv[1] = (short)f2bf(b1); Bv[2] = (short)f2bf(b2); Bv[3] = 0;
  *(s16x4*)&VAb[(size_t)n * 64 + t * 4] = A;
  *(s16x4*)&VBb[(size_t)n * 64 + t * 4] = Bv;
}

// ---------------- CSR build (dst-sorted edge order) ----------------
__global__ void k_hist(const int* ei, int* cnt) {
  int e = blockIdx.x * 256 + threadIdx.x;
  atomicAdd(&cnt[ei[kE + e]], 1);
}

__global__ __launch_bounds__(1024) void k_scan(const int* cnt, int* rowstart, int* cursor) {
  __shared__ int part[1024];
  const int t = threadIdx.x;
  const int base = t * 32;
  int loc[32];
  int s = 0;
#pragma unroll
  for (int i = 0; i < 32; i++) { loc[i] = cnt[base + i]; s += loc[i]; }
  part[t] = s;
  __syncthreads();
  for (int off = 1; off < 1024; off <<= 1) {
    int val = (t >= off) ? part[t - off] : 0;
    __syncthreads();
    part[t] += val;
    __syncthreads();
  }
  int run = (t == 0) ? 0 : part[t - 1];
#pragma unroll
  for (int i = 0; i < 32; i++) {
    rowstart[base + i] = run;
    cursor[base + i] = run;
    run += loc[i];
  }
  if (t == 1023) rowstart[kN] = run;
}

__global__ void k_scatter(const int* ei, const float* pos, int* cursor,
                          int* prm, int* srcp, float* relp, float* lenp) {
  int e = blockIdx.x * 256 + threadIdx.x;
  int a = ei[e], b = ei[kE + e];
  int p = atomicAdd(&cursor[b], 1);
  prm[p] = e;
  srcp[p] = a;
  float dx = pos[(size_t)b * 3 + 0] - pos[(size_t)a * 3 + 0];
  float dy = pos[(size_t)b * 3 + 1] - pos[(size_t)a * 3 + 1];
  float dz = pos[(size_t)b * 3 + 2] - pos[(size_t)a * 3 + 2];
  float n2 = dx * dx + dy * dy + dz * dz;
  float inv = 1.f / sqrtf(fmaxf(n2, 1e-8f));
  float rx = dx * inv, ry = dy * inv, rz = dz * inv;
  relp[(size_t)p * 3 + 0] = rx; relp[(size_t)p * 3 + 1] = ry; relp[(size_t)p * 3 + 2] = rz;
  lenp[p] = sqrtf(fmaxf(rx * rx + ry * ry + rz * rz, 1e-8f));
}

// MFMA edge encoder: wave handles 16 edges; enc(16x32 rbf) @ eew(32x64), LN+silu epilogue.
__global__ __launch_bounds__(256) void k_enc_mfma(
    const int* __restrict__ prm, const float* __restrict__ edr,
    const float* __restrict__ eew, const float* __restrict__ eeb,
    const float* __restrict__ lg, const float* __restrict__ lb,
    __hip_bfloat16* __restrict__ enc) {
  __shared__ unsigned short eewT[64 * 32];  // [col][k] bf16, 4KB
  const int tid = threadIdx.x;
#pragma unroll
  for (int i = 0; i < 8; i++) {
    int idx = tid + i * 256;  // 2048 elems
    int col = idx >> 5, k = idx & 31;
    eewT[col * 32 + k] = f2bf(eew[k * 64 + col]);
  }
  __syncthreads();

  const int lane = tid & 63, wv = tid >> 6;
  const int g4 = lane >> 4, lc = lane & 15;
  const int e0 = blockIdx.x * 64 + wv * 16;

  const int e = prm[e0 + lc];
  const float d = edr[(size_t)e * 2 + (g4 >> 1)];
  const float c0 = 0.8f * (float)((g4 & 1) * 8);
  bf16x8 af;
#pragma unroll
  for (int j = 0; j < 8; j++) {
    float t = d - (c0 + 0.8f * (float)j);
    af[j] = (short)f2bf(__expf(-kGamma * t * t));
  }
  const f32x4 z = {0.f, 0.f, 0.f, 0.f};
  f32x4 acc[4];
#pragma unroll
  for (int ct = 0; ct < 4; ct++)
    acc[ct] = MFMA16(af, *(const bf16x8*)&eewT[(ct * 16 + lc) * 32 + g4 * 8], z);

  float bias4[4], g4v[4], b4[4];
#pragma unroll
  for (int ct = 0; ct < 4; ct++) {
    int col = ct * 16 + lc;
    bias4[ct] = eeb[col]; g4v[ct] = lg[col]; b4[ct] = lb[col];
  }
  float rsum[4] = {0.f, 0.f, 0.f, 0.f}, rsq[4] = {0.f, 0.f, 0.f, 0.f};
#pragma unroll
  for (int ct = 0; ct < 4; ct++)
#pragma unroll
    for (int i = 0; i < 4; i++) {
      float x = acc[ct][i] + bias4[ct];
      acc[ct][i] = x; rsum[i] += x; rsq[i] += x * x;
    }
#pragma unroll
  for (int m = 1; m < 16; m <<= 1)
#pragma unroll
    for (int i = 0; i < 4; i++) {
      rsum[i] += __shfl_xor(rsum[i], m);
      rsq[i] += __shfl_xor(rsq[i], m);
    }
#pragma unroll
  for (int i = 0; i < 4; i++) {
    float mu = rsum[i] * (1.f / 64.f);
    float rs = rsqrtf(rsq[i] * (1.f / 64.f) - mu * mu + kLnEps);
    const size_t row = (size_t)(e0 + g4 * 4 + i);
#pragma unroll
    for (int ct = 0; ct < 4; ct++) {
      float y = (acc[ct][i] - mu) * rs * g4v[ct] + b4[ct];
      enc[row * 64 + ct * 16 + lc] = __float2bfloat16(siluf(y));
    }
  }
}

// ---------------- fused per-dst-node message + in-register aggregation (R7) ----------------
struct __align__(16) EMS2 {
  unsigned short we1T[128 * 72];    // 18432 B
  unsigned short w2T[128 * 136];    // 34816 B
  unsigned short w2gwT[16 * 72];    // 2304 B  (w2@gw composed gate weights)
  unsigned short h[8][16 * 72];     // 18432 B per-wave two-pass scratch
  float wlen[128];
  float b2[128];
  float gb[16];                     // gb2 = gb + b2@gw
  float vw32[16];
};  // 75136 B -> 2 blocks/CU (16 waves/CU)

__global__ __launch_bounds__(512, 4) void k_node_msg(
    const unsigned short* __restrict__ Pb, const unsigned short* __restrict__ Qb,
    const unsigned short* __restrict__ VAb, const unsigned short* __restrict__ VBb,
    const __hip_bfloat16* __restrict__ enc_, const float* __restrict__ relp,
    const float* __restrict__ lenp, const int* __restrict__ srcp,
    const int* __restrict__ rowstart, const float* __restrict__ vglob,
    const float* __restrict__ w1, const float* __restrict__ w2g,
    const float* __restrict__ b2g, const float* __restrict__ w2gw,
    const float* __restrict__ vwg,
    float* __restrict__ aggs, float* __restrict__ aggv, float* __restrict__ vnu) {
  __shared__ EMS2 sm;
  const int tid = threadIdx.x;
  const unsigned short* enc = (const unsigned short*)enc_;

#pragma unroll
  for (int i = 0; i < 16; i++) {
    int idx = tid + i * 512; int k = idx >> 7, n = idx & 127;
    sm.we1T[n * 72 + k] = f2bf(w1[(size_t)(256 + k) * 128 + n]);
  }
#pragma unroll
  for (int i = 0; i < 32; i++) {
    int idx = tid + i * 512; int k = idx >> 7, n = idx & 127;
    sm.w2T[n * 136 + k] = f2bf(w2g[(size_t)k * 128 + n]);
  }
#pragma unroll
  for (int i = 0; i < 4; i++) {
    int idx = tid + i * 512; int k = idx >> 4, t = idx & 15;
    sm.w2gwT[t * 72 + k] = f2bf(w2gw[k * 16 + t]);
  }
  if (tid < 128) { sm.wlen[tid] = w1[320 * 128 + tid] + w1[353 * 128 + tid]; sm.b2[tid] = b2g[tid]; }
  if (tid < 16) { sm.gb[tid] = w2gw[2048 + tid]; sm.vw32[tid] = vwg[512 + tid]; }
  __syncthreads();

  const int lane = tid & 63, wv = tid >> 6;
  const int g4 = lane >> 4;
  const int lc = lane & 15;
  unsigned short* hrow = &sm.h[wv][0];

  float wlenR[8], b2R[8];
#pragma unroll
  for (int nt = 0; nt < 8; nt++) { wlenR[nt] = sm.wlen[lc + 16 * nt]; b2R[nt] = sm.b2[lc + 16 * nt]; }
  const float gbR = sm.gb[lc];
  const float vwR = sm.vw32[lc];
  const f32x4 z = {0.f, 0.f, 0.f, 0.f};

  for (int n = blockIdx.x * 8 + wv; n < kN; n += gridDim.x * 8) {
    const int r0 = rowstart[n], r1 = rowstart[n + 1];
    float qR[8], vbR[3];
    {
      const bf16x8 qv = *(const bf16x8*)&Qb[(size_t)n * 128 + lc * 8];
#pragma unroll
      for (int nt = 0; nt < 8; nt++) qR[nt] = b2f((unsigned short)qv[nt]);
      const s16x4 vbv = *(const s16x4*)&VBb[(size_t)n * 64 + lc * 4];
#pragma unroll
      for (int j = 0; j < 3; j++) vbR[j] = b2f((unsigned short)vbv[j]);
    }
    float colsum[8];
#pragma unroll
    for (int nt = 0; nt < 8; nt++) colsum[nt] = 0.f;
    float av0 = 0.f, av1 = 0.f, av2 = 0.f;

    for (int base = r0; base < r1; base += 16) {
      int nv = r1 - base; if (nv > 16) nv = 16;

      int pa = base + lc; if (pa >= kE) pa = kE - 1;
      const bf16x8 a0 = *(const bf16x8*)&enc[(size_t)pa * 64 + g4 * 8];
      const bf16x8 a1 = *(const bf16x8*)&enc[(size_t)pa * 64 + 32 + g4 * 8];
      f32x4 acc[8];
#pragma unroll
      for (int nt = 0; nt < 8; nt++) {
        acc[nt] = MFMA16(a0, *(const bf16x8*)&sm.we1T[(lc + 16 * nt) * 72 + g4 * 8], z);
        acc[nt] = MFMA16(a1, *(const bf16x8*)&sm.we1T[(lc + 16 * nt) * 72 + 32 + g4 * 8], acc[nt]);
      }

      int sn[4], pr[4]; float le[4];
#pragma unroll
      for (int i = 0; i < 4; i++) {
        int p = base + g4 * 4 + i; if (p >= kE) p = kE - 1;
        pr[i] = p; sn[i] = srcp[p]; le[i] = lenp[p];
      }
      // P[src] gather: one 16B load per edge per lane (swizzled bf16 row)
#pragma unroll
      for (int i = 0; i < 4; i++) {
        const bf16x8 pbv = *(const bf16x8*)&Pb[(size_t)sn[i] * 128 + lc * 8];
#pragma unroll
        for (int nt = 0; nt < 8; nt++)
          acc[nt][i] += b2f((unsigned short)pbv[nt]) + qR[nt] + le[i] * wlenR[nt];
      }

      // stage B two-pass: m = silu(h)(16x128) @ w2 + b2; gate fused via w2@gw
      f32x4 m[8]; f32x4 gac;
#pragma unroll
      for (int i = 0; i < 4; i++)
#pragma unroll
        for (int nt = 0; nt < 4; nt++)
          hrow[(g4 * 4 + i) * 72 + lc + 16 * nt] = f2bf(siluf(acc[nt][i]));
      {
        const bf16x8 aB0 = *(const bf16x8*)&hrow[lc * 72 + g4 * 8];
        const bf16x8 aB1 = *(const bf16x8*)&hrow[lc * 72 + 32 + g4 * 8];
#pragma unroll
        for (int nt = 0; nt < 8; nt++) {
          m[nt] = MFMA16(aB0, *(const bf16x8*)&sm.w2T[(lc + 16 * nt) * 136 + g4 * 8], z);
          m[nt] = MFMA16(aB1, *(const bf16x8*)&sm.w2T[(lc + 16 * nt) * 136 + 32 + g4 * 8], m[nt]);
        }
        gac = MFMA16(aB0, *(const bf16x8*)&sm.w2gwT[lc * 72 + g4 * 8], z);
        gac = MFMA16(aB1, *(const bf16x8*)&sm.w2gwT[lc * 72 + 32 + g4 * 8], gac);
      }
#pragma unroll
      for (int i = 0; i < 4; i++)
#pragma unroll
        for (int nt = 4; nt < 8; nt++)
          hrow[(g4 * 4 + i) * 72 + lc + 16 * (nt - 4)] = f2bf(siluf(acc[nt][i]));
      {
        const bf16x8 aB2 = *(const bf16x8*)&hrow[lc * 72 + g4 * 8];
        const bf16x8 aB3 = *(const bf16x8*)&hrow[lc * 72 + 32 + g4 * 8];
#pragma unroll
        for (int nt = 0; nt < 8; nt++) {
          m[nt] = MFMA16(aB2, *(const bf16x8*)&sm.w2T[(lc + 16 * nt) * 136 + 64 + g4 * 8], m[nt]);
          m[nt] = MFMA16(aB3, *(const bf16x8*)&sm.w2T[(lc + 16 * nt) * 136 + 96 + g4 * 8], m[nt]);
        }
        gac = MFMA16(aB2, *(const bf16x8*)&sm.w2gwT[lc * 72 + 64 + g4 * 8], gac);
        gac = MFMA16(aB3, *(const bf16x8*)&sm.w2gwT[lc * 72 + 96 + g4 * 8], gac);
      }
#pragma unroll
      for (int nt = 0; nt < 8; nt++) {
#pragma unroll
        for (int i = 0; i < 4; i++) m[nt][i] += b2R[nt];
      }

      // accumulate valid rows in registers
#pragma unroll
      for (int i = 0; i < 4; i++) {
        const int row = g4 * 4 + i;
        if (row < nv) {
#pragma unroll
          for (int nt = 0; nt < 8; nt++) colsum[nt] += m[nt][i];
          float g = sigmf(gac[i] + gbR);
          const s16x4 vav = *(const s16x4*)&VAb[(size_t)sn[i] * 64 + lc * 4];
          const float* rp = &relp[(size_t)pr[i] * 3];
          av0 += g * (b2f((unsigned short)vav[0]) + vbR[0] + rp[0] * vwR);
          av1 += g * (b2f((unsigned short)vav[1]) + vbR[1] + rp[1] * vwR);
          av2 += g * (b2f((unsigned short)vav[2]) + vbR[2] + rp[2] * vwR);
        }
      }
    }

#pragma unroll
    for (int nt = 0; nt < 8; nt++) {
      colsum[nt] += __shfl_xor(colsum[nt], 16);
      colsum[nt] += __shfl_xor(colsum[nt], 32);
    }
    av0 += __shfl_xor(av0, 16); av0 += __shfl_xor(av0, 32);
    av1 += __shfl_xor(av1, 16); av1 += __shfl_xor(av1, 32);
    av2 += __shfl_xor(av2, 16); av2 += __shfl_xor(av2, 32);

    if (g4 == 0) {
#pragma unroll
      for (int nt = 0; nt < 8; nt++) aggs[(size_t)n * 128 + lc + 16 * nt] = colsum[nt];
      aggv[(size_t)n * 48 + lc * 3 + 0] = av0;
      aggv[(size_t)n * 48 + lc * 3 + 1] = av1;
      aggv[(size_t)n * 48 + lc * 3 + 2] = av2;
      vnu[(size_t)n * 32 + 16 + lc] = sqrtf(fmaxf(av0 * av0 + av1 * av1 + av2 * av2, 1e-8f));
    } else if (g4 == 1) {
      float x0 = vglob[(size_t)n * 48 + lc * 3 + 0];
      float x1 = vglob[(size_t)n * 48 + lc * 3 + 1];
      float x2 = vglob[(size_t)n * 48 + lc * 3 + 2];
      vnu[(size_t)n * 32 + lc] = sqrtf(fmaxf(x0 * x0 + x1 * x1 + x2 * x2, 1e-8f));
    }
  }
}

// ---------------- fused node update: hupd GEMM (K=288) + ds GEMM (K=128) + epilogue ----------
__global__ __launch_bounds__(256) void k_upd_fused(
    const float* __restrict__ sA, const float* __restrict__ aggS,
    const float* __restrict__ vnu, const unsigned short* __restrict__ B4T,
    const float* __restrict__ ub1, const unsigned short* __restrict__ BuT,
    const float* __restrict__ b2,
    const float* __restrict__ ugw, const float* __restrict__ ugb, const float* __restrict__ uvw,
    const float* __restrict__ aggv, const float* __restrict__ lng, const float* __restrict__ lnb,
    float* __restrict__ s, float* __restrict__ v, float* __restrict__ vnout) {
  __shared__ __align__(16) float dsb[64 * 129];          // 33024 B
  __shared__ __align__(16) unsigned short hb[64 * 136];  // 17408 B
  __shared__ float smu[64], srs[64];
  __shared__ float uvwS[512];
  const int tid = threadIdx.x;
  const int bm = blockIdx.x * 64;
  const int lane = tid & 63, wv = tid >> 6;
  const int g4 = lane >> 4, lc = lane & 15;
  uvwS[tid] = uvw[tid]; uvwS[tid + 256] = uvw[tid + 256];
  const f32x4 z = {0.f, 0.f, 0.f, 0.f};
  const int r = bm + wv * 16 + lc;

  // ---- phase 1: h = silu([s|aggS|vnu] @ uw1 + ub1), K=288, direct-frag ----
  f32x4 acc[8];
#pragma unroll
  for (int nt = 0; nt < 8; nt++) acc[nt] = z;
#pragma unroll
  for (int ks = 0; ks < 9; ks++) {
    const int k = ks * 32 + g4 * 8;
    const float* ap = (k < 128) ? sA + (size_t)r * 128 + k
                    : (k < 256) ? aggS + (size_t)r * 128 + (k - 128)
                                : vnu + (size_t)r * 32 + (k - 256);
    const bf16x8 af = ldA(ap);
#pragma unroll
    for (int nt = 0; nt < 8; nt++)
      acc[nt] = MFMA16(af, *(const bf16x8*)&B4T[(lc + 16 * nt) * 288 + k], acc[nt]);
  }
#pragma unroll
  for (int nt = 0; nt < 8; nt++) {
    float bv = ub1[lc + 16 * nt];
#pragma unroll
    for (int i = 0; i < 4; i++)
      hb[(wv * 16 + g4 * 4 + i) * 136 + lc + 16 * nt] = f2bf(siluf(acc[nt][i] + bv));
  }
  __syncthreads();

  // ---- phase 2: ds = h @ uw2 + ub2, K=128, A-frags from LDS ----
  f32x4 acc2[8];
#pragma unroll
  for (int nt = 0; nt < 8; nt++) acc2[nt] = z;
#pragma unroll
  for (int ks = 0; ks < 4; ks++) {
    const int k = ks * 32 + g4 * 8;
    const bf16x8 af = *(const bf16x8*)&hb[(wv * 16 + lc) * 136 + k];
#pragma unroll
    for (int nt = 0; nt < 8; nt++)
      acc2[nt] = MFMA16(af, *(const bf16x8*)&BuT[(lc + 16 * nt) * 128 + k], acc2[nt]);
  }
#pragma unroll
  for (int nt = 0; nt < 8; nt++) {
    float bv = b2[lc + 16 * nt];
#pragma unroll
    for (int i = 0; i < 4; i++)
      dsb[(wv * 16 + g4 * 4 + i) * 129 + lc + 16 * nt] = acc2[nt][i] + bv;
  }
  __syncthreads();

  // ---- epilogue: gates, v update, s = LN(s+ds), vn for next layer ----
  const int rr = tid >> 2, p = tid & 3;
  const int n = bm + rr;
  float g[4];
#pragma unroll
  for (int j = 0; j < 4; j++) g[j] = ugb[p * 4 + j];
#pragma unroll 8
  for (int k = 0; k < 128; k++) {
    float m = dsb[rr * 129 + k];
    const float4 wg = *(const float4*)&ugw[k * 16 + p * 4];
    g[0] += m * wg.x; g[1] += m * wg.y; g[2] += m * wg.z; g[3] += m * wg.w;
  }
#pragma unroll
  for (int j = 0; j < 4; j++) g[j] = sigmf(g[j]);

  float vnew[12];
#pragma unroll
  for (int i2 = 0; i2 < 3; i2++) {
    float xv[16], xa[16];
#pragma unroll
    for (int c = 0; c < 16; c++) {
      xv[c] = v[(size_t)n * 48 + c * 3 + i2];
      xa[c] = aggv[(size_t)n * 48 + c * 3 + i2];
    }
#pragma unroll
    for (int j = 0; j < 4; j++) {
      int t = p * 4 + j;
      float a = 0.f;
#pragma unroll
      for (int c = 0; c < 16; c++)
        a += xv[c] * uvwS[c * 16 + t] + xa[c] * uvwS[(16 + c) * 16 + t];
      vnew[j * 3 + i2] = xv[t] + a * g[j];
    }
  }
  if (tid < 64) {
    float sm = 0.f, sq = 0.f;
    for (int c = 0; c < 128; c++) {
      float x = s[(size_t)(bm + tid) * 128 + c] + dsb[tid * 129 + c];
      sm += x; sq += x * x;
    }
    float mu = sm * (1.f / 128.f);
    float var = sq * (1.f / 128.f) - mu * mu;
    smu[tid] = mu; srs[tid] = rsqrtf(var + kLnEps);
  }
  __syncthreads();
#pragma unroll
  for (int j = 0; j < 4; j++) {
    float n0 = vnew[j * 3 + 0], n1 = vnew[j * 3 + 1], n2 = vnew[j * 3 + 2];
#pragma unroll
    for (int i2 = 0; i2 < 3; i2++)
      v[(size_t)n * 48 + (p * 4 + j) * 3 + i2] = vnew[j * 3 + i2];
    vnout[(size_t)n * 32 + p * 4 + j] = sqrtf(fmaxf(n0 * n0 + n1 * n1 + n2 * n2, 1e-8f));
    vnout[(size_t)n * 32 + 16 + p * 4 + j] = 0.f;
  }
#pragma unroll 4
  for (int i = 0; i < 32; i++) {
    int idx = tid + i * 256; int rw = idx >> 7, c = idx & 127;
    float x = s[(size_t)(bm + rw) * 128 + c] + dsb[rw * 129 + c];
    float y = (x - smu[rw]) * srs[rw] * lng[c] + lnb[c];
    s[(size_t)(bm + rw) * 128 + c] = y;
  }
}

// ---------------- pooling + heads ----------------
DI int lbound(const int* b, int nn, int key) {
  int lo = 0, hi = nn;
  while (lo < hi) { int m = (lo + hi) >> 1; if (b[m] < key) lo = m + 1; else hi = m; }
  return lo;
}

__global__ void k_pool(const float* s, const int* batch, float* dout) {
  int g = blockIdx.x, tid = threadIdx.x;  // 128 threads
  int lo = lbound(batch, kN, g), hi = lbound(batch, kN, g + 1);
  float sum = 0.f, mx = -3.402823e38f;
  for (int n = lo; n < hi; n++) {
    float x = s[(size_t)n * 128 + tid];
    sum += x; mx = fmaxf(mx, x);
  }
  int cnt = hi - lo;
  float mean = sum / fmaxf((float)cnt, 1.f);
  if (cnt == 0) mx = 0.f;
  dout[960 + g * 256 + tid] = mean;
  dout[960 + g * 256 + 128 + tid] = mx;
}

__global__ void k_heads(const float* hw1, const float* hb1, const float* hw2, const float* hb2,
                        const float* ew1, const float* eb1, const float* ew2, const float* eb2,
                        float* dout) {
  __shared__ float emb[256], h1[256];
  int g = blockIdx.x, tid = threadIdx.x;  // 128 threads
  emb[tid] = dout[960 + g * 256 + tid];
  emb[128 + tid] = dout[960 + g * 256 + 128 + tid];
  __syncthreads();
  float am = hb1[tid], ae = eb1[tid];
#pragma unroll 4
  for (int k = 0; k < 256; k++) {
    float e = emb[k];
    am += e * hw1[k * 128 + tid];
    ae += e * ew1[k * 128 + tid];
  }
  h1[tid] = siluf(am); h1[128 + tid] = siluf(ae);
  __syncthreads();
  if (tid < 8) {
    float a = hb2[tid];
    for (int j = 0; j < 128; j++) a += h1[j] * hw2[j * 8 + tid];
    dout[g * 8 + tid] = a;
  } else if (tid >= 64 && tid < 71) {
    int o = tid - 64;
    float a = eb2[o];
    for (int j = 0; j < 128; j++) a += h1[128 + j] * ew2[j * 7 + o];
    dout[512 + g * 7 + o] = a;
  }
}

// ---------------- launcher ----------------
extern "C" void kernel_launch(void* const* d_in, const int* in_sizes, int n_in,
                              void* d_out, int out_size, void* d_ws, size_t ws_size,
                              hipStream_t stream) {
  (void)in_sizes; (void)n_in; (void)out_size; (void)ws_size;
  const float* x_esm   = (const float*)d_in[0];
  const float* x_resch = (const float*)d_in[1];
  const float* x_role  = (const float*)d_in[2];
  const float* x_dist  = (const float*)d_in[3];
  const float* x_misc  = (const float*)d_in[4];
  const float* x_vec   = (const float*)d_in[5];
  const float* pos     = (const float*)d_in[6];
  const float* edr     = (const float*)d_in[7];
  const float* ne_esm_w = (const float*)d_in[8];
  const float* ne_esm_b = (const float*)d_in[9];
  const float* ne_esm_lg = (const float*)d_in[10];
  const float* ne_esm_lb = (const float*)d_in[11];
  const float* ne_out_w = (const float*)d_in[12];
  const float* ne_out_b = (const float*)d_in[13];
  const float* ne_out_lg = (const float*)d_in[14];
  const float* ne_out_lb = (const float*)d_in[15];
  const float* ee_w = (const float*)d_in[16];
  const float* ee_b = (const float*)d_in[17];
  const float* ee_lg = (const float*)d_in[18];
  const float* ee_lb = (const float*)d_in[19];
  const float* ivw = (const float*)d_in[20];
  const float* msg_w1 = (const float*)d_in[21];
  const float* msg_b1 = (const float*)d_in[22];
  const float* msg_w2 = (const float*)d_in[23];
  const float* msg_b2 = (const float*)d_in[24];
  const float* msg_vw = (const float*)d_in[25];
  const float* msg_gw = (const float*)d_in[26];
  const float* msg_gb = (const float*)d_in[27];
  const float* upd_w1 = (const float*)d_in[28];
  const float* upd_b1 = (const float*)d_in[29];
  const float* upd_w2 = (const float*)d_in[30];
  const float* upd_b2 = (const float*)d_in[31];
  const float* upd_vw = (const float*)d_in[32];
  const float* upd_gw = (const float*)d_in[33];
  const float* upd_gb = (const float*)d_in[34];
  const float* ln_g = (const float*)d_in[35];
  const float* ln_b = (const float*)d_in[36];
  const float* hm_w1 = (const float*)d_in[37];
  const float* hm_b1 = (const float*)d_in[38];
  const float* hm_w2 = (const float*)d_in[39];
  const float* hm_b2 = (const float*)d_in[40];
  const float* he_w1 = (const float*)d_in[41];
  const float* he_b1 = (const float*)d_in[42];
  const float* he_w2 = (const float*)d_in[43];
  const float* he_b2 = (const float*)d_in[44];
  const int* ei = (const int*)d_in[45];
  const int* batch = (const int*)d_in[46];
  float* dout = (float*)d_out;

  // workspace layout
  size_t off = 0;
  auto alloc = [&](size_t bytes) {
    void* p = (char*)d_ws + off;
    off += (bytes + 255) & ~(size_t)255;
    return p;
  };
  float* s    = (float*)alloc((size_t)kN * 128 * 4);
  float* v    = (float*)alloc((size_t)kN * 48 * 4);
  float* vn   = (float*)alloc((size_t)kN * 32 * 4);      // padded to 32
  unsigned short* Pb = (unsigned short*)alloc((size_t)kN * 128 * 2);
  unsigned short* Qb = (unsigned short*)alloc((size_t)kN * 128 * 2);
  unsigned short* VAb = (unsigned short*)alloc((size_t)kN * 64 * 2);
  unsigned short* VBb = (unsigned short*)alloc((size_t)kN * 64 * 2);
  float* aggS = (float*)alloc((size_t)kN * 128 * 4);
  float* aggV = (float*)alloc((size_t)kN * 48 * 4);
  float* vnu  = (float*)alloc((size_t)kN * 32 * 4);
  float* hupd = (float*)alloc((size_t)kN * 128 * 4);     // esm (pre-layers)
  float* xrest = (float*)alloc((size_t)kN * 96 * 4);
  __hip_bfloat16* enc = (__hip_bfloat16*)alloc((size_t)kE * 64 * 2);
  float* relp = (float*)alloc((size_t)kE * 3 * 4);
  float* lenp = (float*)alloc((size_t)kE * 4);
  int* srcp   = (int*)alloc((size_t)kE * 4);
  int* prm    = (int*)alloc((size_t)kE * 4);
  int* cnt    = (int*)alloc((size_t)kN * 4);
  int* rowstart = (int*)alloc((size_t)(kN + 1) * 4);
  int* cursor = (int*)alloc((size_t)kN * 4);
  unsigned short* B0T = (unsigned short*)alloc((size_t)128 * 1280 * 2);
  unsigned short* B1T = (unsigned short*)alloc((size_t)128 * 224 * 2);
  unsigned short* B23T = (unsigned short*)alloc((size_t)kL * 256 * 160 * 2);
  unsigned short* B4T = (unsigned short*)alloc((size_t)kL * 128 * 288 * 2);
  unsigned short* BuT = (unsigned short*)alloc((size_t)kL * 128 * 128 * 2);
  float* w2gwL = (float*)alloc((size_t)kL * 2064 * 4);
  float* esm = hupd;

  // ---- one-time: CSR build, B^T weights, composed gate weights, feature blocks ----
  hipMemsetAsync(cnt, 0, (size_t)kN * 4, stream);
  k_hist<<<kE / 256, 256, 0, stream>>>(ei, cnt);
  k_scan<<<1, 1024, 0, stream>>>(cnt, rowstart, cursor);
  k_scatter<<<kE / 256, 256, 0, stream>>>(ei, pos, cursor, prm, srcp, relp, lenp);
  k_enc_mfma<<<kE / 64, 256, 0, stream>>>(prm, edr, ee_w, ee_b, ee_lg, ee_lb, enc);
  k_btA<<<(1280 * 128 + 255) / 256, 256, 0, stream>>>(ne_esm_w, B0T, 1280);
  k_bt1<<<(224 * 128 + 255) / 256, 256, 0, stream>>>(ne_out_w, B1T);
  k_xrest<<<(kN * 96 + 255) / 256, 256, 0, stream>>>(x_resch, x_role, x_misc, x_dist, xrest);
  for (int l = 0; l < kL; l++) {
    k_btPQ<<<(256 * 160 + 255) / 256, 256, 0, stream>>>(msg_w1 + (size_t)l * 354 * 128,
                                                        B23T + (size_t)l * 256 * 160);
    k_btA<<<(288 * 128 + 255) / 256, 256, 0, stream>>>(upd_w1 + (size_t)l * 288 * 128,
                                                       B4T + (size_t)l * 128 * 288, 288);
    k_btA<<<(128 * 128 + 255) / 256, 256, 0, stream>>>(upd_w2 + (size_t)l * 128 * 128,
                                                       BuT + (size_t)l * 128 * 128, 128);
    k_w2gw<<<9, 256, 0, stream>>>(msg_w2 + (size_t)l * 128 * 128, msg_gw + l * 128 * 16,
                                  msg_b2 + l * 128, msg_gb + l * 16, w2gwL + (size_t)l * 2064);
  }

  // ---- encoders ----
  {
    G2 p{}; p.A1 = x_esm; p.BT = B0T; p.out = esm;
    p.bias = ne_esm_b; p.lng = ne_esm_lg; p.lnb = ne_esm_lb;
    k_gemm2<0><<<kN / 64, 256, 0, stream>>>(p);
  }
  {
    G2 p{}; p.A1 = esm; p.A2 = xrest; p.BT = B1T; p.out = s;
    p.bias = ne_out_b; p.lng = ne_out_lg; p.lnb = ne_out_lb;
    k_gemm2<1><<<kN / 64, 256, 0, stream>>>(p);
  }
  k_v0<<<kN * 48 / 256, 256, 0, stream>>>(x_vec, ivw, v);
  k_vn<<<kN * 32 / 256, 256, 0, stream>>>(v, vn);

  // ---- message passing layers ----
  for (int l = 0; l < kL; l++) {
    const float* w1l = msg_w1 + (size_t)l * 354 * 128;
    const float* b1l = msg_b1 + l * 128;
    const float* w2l = msg_w2 + (size_t)l * 128 * 128;
    const float* b2l = msg_b2 + l * 128;
    const float* vwl = msg_vw + l * 33 * 16;
    const float* ub1 = upd_b1 + l * 128;
    const float* ub2 = upd_b2 + l * 128;
    const float* uvwl = upd_vw + l * 32 * 16;
    const float* ugwl = upd_gw + l * 128 * 16;
    const float* ugbl = upd_gb + l * 16;
    const float* lgl = ln_g + l * 128;
    const float* lbl = ln_b + l * 128;

    {
      G2 p{}; p.A1 = s; p.A2 = vn; p.BT = B23T + (size_t)l * 256 * 160;
      p.obfP = Pb; p.obfQ = Qb; p.bias = b1l;
      k_gemm2<2><<<kN / 64, 256, 0, stream>>>(p);
    }
    k_vab<<<kN * 16 / 256, 256, 0, stream>>>(v, vwl, VAb, VBb);
    k_node_msg<<<512, 512, 0, stream>>>(Pb, Qb, VAb, VBb, enc, relp, lenp, srcp,
                                        rowstart, v, w1l, w2l, b2l,
                                        w2gwL + (size_t)l * 2064, vwl,
                                        aggS, aggV, vnu);
    k_upd_fused<<<kN / 64, 256, 0, stream>>>(s, aggS, vnu,
                                             B4T + (size_t)l * 128 * 288, ub1,
                                             BuT + (size_t)l * 128 * 128, ub2,
                                             ugwl, ugbl, uvwl, aggV, lgl, lbl, s, v, vn);
  }

  // ---- pooling + heads ----
  k_pool<<<kB, 128, 0, stream>>>(s, batch, dout);
  k_heads<<<kB, 128, 0, stream>>>(hm_w1, hm_b1, hm_w2, hm_b2,
                                  he_w1, he_b1, he_w2, he_b2, dout);
}